// Round 5
// baseline (1898.562 us; speedup 1.0000x reference)
//
#include <hip/hip_runtime.h>
#include <hip/hip_bf16.h>

#define TT 4096
#define BB 256
#define DD 3
#define UU 8

// ---------- fast activations ----------
#if defined(__has_builtin)
#if __has_builtin(__builtin_amdgcn_exp2f) && __has_builtin(__builtin_amdgcn_rcpf)
#define FAST_EXP2(x) __builtin_amdgcn_exp2f(x)
#define FAST_RCP(x)  __builtin_amdgcn_rcpf(x)
#endif
#endif
#ifndef FAST_EXP2
#define FAST_EXP2(x) exp2f(x)
#define FAST_RCP(x)  (1.0f / (x))
#endif

#define NLOG2E  (-1.4426950408889634f)
#define P2LOG2E ( 2.8853900817779268f)

__device__ __forceinline__ float fsig(float x) {
    float e = FAST_EXP2(NLOG2E * x);
    return FAST_RCP(1.0f + e);
}
__device__ __forceinline__ float ftanh(float x) {
    float e = FAST_EXP2(P2LOG2E * x);
    return 1.0f - 2.0f * FAST_RCP(1.0f + e);
}

// ---------- DPP helpers ----------
template <int CTRL>
__device__ __forceinline__ float dpp_f(float v) {
    int i = __builtin_bit_cast(int, v);
    i = __builtin_amdgcn_update_dpp(0, i, CTRL, 0xF, 0xF, true);
    return __builtin_bit_cast(float, i);
}

// ---------- block-wide exclusive scan over 256 threads (R1/R2 verbatim) ----------
__device__ __forceinline__ float block_excl_scan(float v, int tid, float* red) {
    float x = v;
    int lid = tid & 63;
    #pragma unroll
    for (int d = 1; d < 64; d <<= 1) {
        float y = __shfl_up(x, d, 64);
        if (lid >= d) x += y;
    }
    int wave = tid >> 6;
    __syncthreads();
    if (lid == 63) red[wave] = x;
    __syncthreads();
    float off = 0.0f;
    for (int w = 0; w < wave; ++w) off += red[w];
    return off + (x - v);
}

// ---------- Kernel A: R1/R2-measured-best structure; only the store scales gates ----------
// ws layout: [t][b][u] float4 = {-L*gi_pre, 2L*gc_pre, -L*go_pre, f_sigmoided}
__global__ __launch_bounds__(256) void sig_pre_kernel(
    const float* __restrict__ x,     // (B,T,3)
    const float* __restrict__ Wi,    // (3,24)
    const float* __restrict__ Wf,    // (21,8)
    const float* __restrict__ bias,  // (32)
    float* __restrict__ ws)
{
    __shared__ float sWf[21 * 8];
    __shared__ float sWi[3 * 24];
    __shared__ float sB[32];
    __shared__ float red[4];

    const int tid = threadIdx.x;
    const int b = blockIdx.x;
    if (tid < 168) sWf[tid] = Wf[tid];
    if (tid < 72)  sWi[tid] = Wi[tid];
    if (tid < 32)  sB[tid]  = bias[tid];
    __syncthreads();

    const float dtc = 1.0f / 4095.0f;
    const int t0 = tid * 16;
    const float* xb = x + (size_t)b * TT * DD;

    float l1[4] = {0.f, 0.f, 0.f, 0.f};
    float l2[16];
    #pragma unroll
    for (int i = 0; i < 16; ++i) l2[i] = 0.f;
    {
        int s = (tid == 0) ? 1 : t0;
        float xp0 = xb[(s - 1) * 3 + 0];
        float xp1 = xb[(s - 1) * 3 + 1];
        float xp2 = xb[(s - 1) * 3 + 2];
        for (; s < t0 + 16; ++s) {
            float c0 = xb[s * 3 + 0], c1 = xb[s * 3 + 1], c2 = xb[s * 3 + 2];
            float dxv[4] = {dtc, c0 - xp0, c1 - xp1, c2 - xp2};
            #pragma unroll
            for (int r = 0; r < 4; ++r) {
                float tr = l1[r] + 0.5f * dxv[r];
                #pragma unroll
                for (int cc = 0; cc < 4; ++cc)
                    l2[r * 4 + cc] = fmaf(tr, dxv[cc], l2[r * 4 + cc]);
            }
            #pragma unroll
            for (int r = 0; r < 4; ++r) l1[r] += dxv[r];
            xp0 = c0; xp1 = c1; xp2 = c2;
        }
    }

    float S1[4], O1[4];
    #pragma unroll
    for (int r = 0; r < 4; ++r) { S1[r] = l1[r]; }
    for (int r = 0; r < 4; ++r) O1[r] = block_excl_scan(S1[r], tid, red);
    float O2[16];
    for (int rc = 0; rc < 16; ++rc) {
        float c2v = l2[rc] + O1[rc >> 2] * S1[rc & 3];
        O2[rc] = block_excl_scan(c2v, tid, red);
    }

    #pragma unroll
    for (int r = 0; r < 4; ++r) l1[r] = O1[r];
    #pragma unroll
    for (int i = 0; i < 16; ++i) l2[i] = O2[i];

    float xp0, xp1, xp2;
    {
        int tp = (tid == 0) ? 0 : (t0 - 1);
        xp0 = xb[tp * 3 + 0]; xp1 = xb[tp * 3 + 1]; xp2 = xb[tp * 3 + 2];
    }
    for (int i2 = 0; i2 < 16; ++i2) {
        const int t = t0 + i2;
        float c0 = xb[t * 3 + 0], c1 = xb[t * 3 + 1], c2 = xb[t * 3 + 2];
        if (t > 0) {
            float dxv[4] = {dtc, c0 - xp0, c1 - xp1, c2 - xp2};
            #pragma unroll
            for (int r = 0; r < 4; ++r) {
                float tr = l1[r] + 0.5f * dxv[r];
                #pragma unroll
                for (int cc = 0; cc < 4; ++cc)
                    l2[r * 4 + cc] = fmaf(tr, dxv[cc], l2[r * 4 + cc]);
            }
            #pragma unroll
            for (int r = 0; r < 4; ++r) l1[r] += dxv[r];
        }
        xp0 = c0; xp1 = c1; xp2 = c2;
        const float scale = (t == 0) ? 1.0f : (4095.0f / (float)t);
        float sg[21];
        sg[0] = scale;
        #pragma unroll
        for (int r = 0; r < 4; ++r) sg[1 + r] = l1[r] * scale;
        #pragma unroll
        for (int rc = 0; rc < 16; ++rc) sg[5 + rc] = l2[rc] * scale;

        float fa[8];
        #pragma unroll
        for (int u = 0; u < 8; ++u) fa[u] = sB[8 + u];
        #pragma unroll
        for (int j = 0; j < 21; ++j) {
            float s = sg[j];
            #pragma unroll
            for (int u = 0; u < 8; ++u) fa[u] = fmaf(s, sWf[j * 8 + u], fa[u]);
        }
        float g[24];
        #pragma unroll
        for (int u = 0; u < 8; ++u) {
            g[u] = sB[u]; g[8 + u] = sB[16 + u]; g[16 + u] = sB[24 + u];
        }
        #pragma unroll
        for (int gg = 0; gg < 24; ++gg) {
            g[gg] = fmaf(c0, sWi[gg], g[gg]);
            g[gg] = fmaf(c1, sWi[24 + gg], g[gg]);
            g[gg] = fmaf(c2, sWi[48 + gg], g[gg]);
        }
        float4* wp = (float4*)ws + ((size_t)t * BB + b) * UU;
        #pragma unroll
        for (int u = 0; u < 8; ++u)
            wp[u] = make_float4(NLOG2E * g[u], P2LOG2E * g[8 + u],
                                NLOG2E * g[16 + u], fsig(fa[u]));
    }
}

// ---------- Kernel B: 4-way interleaved recurrences per lane ----------
// lane = q*8+u; each lane handles unit u of batches b0+{0,8,16,24}; 32 batches/wave.
__global__ __launch_bounds__(64) void lstm_scan_full(
    const float* __restrict__ ws, const float* __restrict__ Wr,
    float* __restrict__ out)
{
    const int lane = threadIdx.x;
    const int u = lane & 7;
    const int q = lane >> 3;
    const int b0 = blockIdx.x * 32 + q;
    // scaled weights: wa,wc *= -log2e ; wb *= 2log2e (source unit j = u^m)
    float wa[8], wb[8], wc[8];
    #pragma unroll
    for (int m = 0; m < 8; ++m) {
        int j = u ^ m;
        wa[m] = NLOG2E  * Wr[j * 24 + u];
        wb[m] = P2LOG2E * Wr[j * 24 + 8 + u];
        wc[m] = NLOG2E  * Wr[j * 24 + 16 + u];
    }
    const float4* gp[4];
    float* op[4];
    float h[4], c[4];
    float4 buf[4][8];
    #pragma unroll
    for (int n = 0; n < 4; ++n) {
        int b = b0 + n * 8;
        gp[n] = (const float4*)ws + (size_t)b * 8 + u;   // + t*2048
        op[n] = out + (size_t)b * TT * 8 + u;
        h[n] = 0.f; c[n] = 0.f;
        #pragma unroll
        for (int p = 0; p < 8; ++p) buf[n][p] = gp[n][(size_t)p * 2048];
    }

    auto round = [&](int t, int j, bool pf) {
        float gx[4], gy[4], gz[4], gw[4];
        #pragma unroll
        for (int n = 0; n < 4; ++n) {
            float4 g = buf[n][j];
            gx[n] = g.x; gy[n] = g.y; gz[n] = g.z; gw[n] = g.w;
        }
        if (pf) {
            #pragma unroll
            for (int n = 0; n < 4; ++n)
                buf[n][j] = gp[n][(size_t)(t + 8) * 2048];
        }
        // stage 1: DPP butterflies (4 independent sets)
        float H[4][8];
        #pragma unroll
        for (int n = 0; n < 4; ++n) {
            H[n][0] = h[n];
            H[n][1] = dpp_f<0xB1>(h[n]);    // xor 1
            H[n][2] = dpp_f<0x4E>(h[n]);    // xor 2
            H[n][3] = dpp_f<0x1B>(h[n]);    // xor 3
            H[n][7] = dpp_f<0x141>(h[n]);   // xor 7
            H[n][6] = dpp_f<0xB1>(H[n][7]); // xor 6
            H[n][5] = dpp_f<0x4E>(H[n][7]); // xor 5
            H[n][4] = dpp_f<0x1B>(H[n][7]); // xor 4
        }
        // stage 2: gate dot products (two 4-chains each, independent across n)
        float gi[4], gcv[4], go[4];
        #pragma unroll
        for (int n = 0; n < 4; ++n) {
            float a0 = fmaf(H[n][0], wa[0], gx[n]), a1 = H[n][4] * wa[4];
            float b0_ = fmaf(H[n][0], wb[0], gy[n]), b1 = H[n][4] * wb[4];
            float c0_ = fmaf(H[n][0], wc[0], gz[n]), c1 = H[n][4] * wc[4];
            a0 = fmaf(H[n][1], wa[1], a0);  a1 = fmaf(H[n][5], wa[5], a1);
            b0_ = fmaf(H[n][1], wb[1], b0_); b1 = fmaf(H[n][5], wb[5], b1);
            c0_ = fmaf(H[n][1], wc[1], c0_); c1 = fmaf(H[n][5], wc[5], c1);
            a0 = fmaf(H[n][2], wa[2], a0);  a1 = fmaf(H[n][6], wa[6], a1);
            b0_ = fmaf(H[n][2], wb[2], b0_); b1 = fmaf(H[n][6], wb[6], b1);
            c0_ = fmaf(H[n][2], wc[2], c0_); c1 = fmaf(H[n][6], wc[6], c1);
            a0 = fmaf(H[n][3], wa[3], a0);  a1 = fmaf(H[n][7], wa[7], a1);
            b0_ = fmaf(H[n][3], wb[3], b0_); b1 = fmaf(H[n][7], wb[7], b1);
            c0_ = fmaf(H[n][3], wc[3], c0_); c1 = fmaf(H[n][7], wc[7], c1);
            gi[n] = a0 + a1; gcv[n] = b0_ + b1; go[n] = c0_ + c1;
        }
        // stage 3: transcendentals (independent across n -> fills latency)
        float ei[4], ec[4], eo[4];
        #pragma unroll
        for (int n = 0; n < 4; ++n) {
            ei[n] = FAST_EXP2(gi[n]);    // e^{-i_pre}
            ec[n] = FAST_EXP2(gcv[n]);   // e^{2 c_pre}
            eo[n] = FAST_EXP2(go[n]);    // e^{-o_pre}
        }
        // stage 4: c update: i*chat = (ec-1)/((1+ei)(1+ec))
        #pragma unroll
        for (int n = 0; n < 4; ++n) {
            float r1 = FAST_RCP((1.0f + ei[n]) * (1.0f + ec[n]));
            c[n] = fmaf(gw[n], c[n], (ec[n] - 1.0f) * r1);
        }
        // stage 5: h = (e2c-1)/((1+eo)(1+e2c)), clamp exp arg
        #pragma unroll
        for (int n = 0; n < 4; ++n) {
            float s3 = fminf(P2LOG2E * c[n], 63.0f);
            float e2 = FAST_EXP2(s3);
            float r2 = FAST_RCP((1.0f + eo[n]) * (1.0f + e2));
            h[n] = (e2 - 1.0f) * r2;
        }
        #pragma unroll
        for (int n = 0; n < 4; ++n)
            op[n][(size_t)t * 8] = h[n];
    };

    for (int tb = 0; tb + 8 <= TT - 8; tb += 8) {
        #pragma unroll
        for (int j = 0; j < 8; ++j) round(tb + j, j, true);
    }
    #pragma unroll
    for (int j = 0; j < 8; ++j) round(TT - 8 + j, j, false);
}

// ---------- Fallback: no-scratch single kernel (raw weights) ----------
__global__ __launch_bounds__(64) void lstm_scan_ultra(
    const float* __restrict__ x, const float* __restrict__ Wi,
    const float* __restrict__ Wr, const float* __restrict__ Wf,
    const float* __restrict__ bias, float* __restrict__ out)
{
    const int lane = threadIdx.x;
    const int u = lane & 7;
    const int q = lane >> 3;
    const int b = blockIdx.x * 8 + q;
    float wa[8], wb[8], wc[8];
    #pragma unroll
    for (int m = 0; m < 8; ++m) {
        int j = u ^ m;
        wa[m] = Wr[j * 24 + u];
        wb[m] = Wr[j * 24 + 8 + u];
        wc[m] = Wr[j * 24 + 16 + u];
    }
    float wia[3], wib[3], wic[3];
    #pragma unroll
    for (int k = 0; k < 3; ++k) {
        wia[k] = Wi[k * 24 + u];
        wib[k] = Wi[k * 24 + 8 + u];
        wic[k] = Wi[k * 24 + 16 + u];
    }
    float wf[21];
    #pragma unroll
    for (int j = 0; j < 21; ++j) wf[j] = Wf[j * 8 + u];
    const float bi = bias[u], bf = bias[8 + u], bc = bias[16 + u], bo = bias[24 + u];
    const float* xb = x + (size_t)b * TT * 3;
    float l1[4] = {0.f, 0.f, 0.f, 0.f};
    float l2[16];
    #pragma unroll
    for (int i = 0; i < 16; ++i) l2[i] = 0.f;
    float xp0 = xb[0], xp1 = xb[1], xp2 = xb[2];
    float h = 0.f, c = 0.f;
    float* op = out + (size_t)b * TT * 8 + u;
    const float dtc = 1.0f / 4095.0f;
    for (int t = 0; t < TT; ++t) {
        float c0 = xb[t * 3 + 0], c1 = xb[t * 3 + 1], c2 = xb[t * 3 + 2];
        if (t > 0) {
            float dxv[4] = {dtc, c0 - xp0, c1 - xp1, c2 - xp2};
            #pragma unroll
            for (int r = 0; r < 4; ++r) {
                float tr = l1[r] + 0.5f * dxv[r];
                #pragma unroll
                for (int cc = 0; cc < 4; ++cc)
                    l2[r * 4 + cc] = fmaf(tr, dxv[cc], l2[r * 4 + cc]);
            }
            #pragma unroll
            for (int r = 0; r < 4; ++r) l1[r] += dxv[r];
        }
        xp0 = c0; xp1 = c1; xp2 = c2;
        const float scale = (t == 0) ? 1.0f : (4095.0f / (float)t);
        float dot = wf[0];
        #pragma unroll
        for (int r = 0; r < 4; ++r) dot = fmaf(l1[r], wf[1 + r], dot);
        #pragma unroll
        for (int rc = 0; rc < 16; ++rc) dot = fmaf(l2[rc], wf[5 + rc], dot);
        float fv = fsig(fmaf(scale, dot, bf));
        float gi = bi, gc = bc, go = bo;
        gi = fmaf(c0, wia[0], gi); gi = fmaf(c1, wia[1], gi); gi = fmaf(c2, wia[2], gi);
        gc = fmaf(c0, wib[0], gc); gc = fmaf(c1, wib[1], gc); gc = fmaf(c2, wib[2], gc);
        go = fmaf(c0, wic[0], go); go = fmaf(c1, wic[1], go); go = fmaf(c2, wic[2], go);
        float h1 = dpp_f<0xB1>(h);
        float h2 = dpp_f<0x4E>(h);
        float h3 = dpp_f<0x1B>(h);
        float h7 = dpp_f<0x141>(h);
        float h6 = dpp_f<0xB1>(h7);
        float h5 = dpp_f<0x4E>(h7);
        float h4 = dpp_f<0x1B>(h7);
        gi = fmaf(h, wa[0], gi); gi = fmaf(h1, wa[1], gi); gi = fmaf(h2, wa[2], gi); gi = fmaf(h3, wa[3], gi);
        gi = fmaf(h4, wa[4], gi); gi = fmaf(h5, wa[5], gi); gi = fmaf(h6, wa[6], gi); gi = fmaf(h7, wa[7], gi);
        gc = fmaf(h, wb[0], gc); gc = fmaf(h1, wb[1], gc); gc = fmaf(h2, wb[2], gc); gc = fmaf(h3, wb[3], gc);
        gc = fmaf(h4, wb[4], gc); gc = fmaf(h5, wb[5], gc); gc = fmaf(h6, wb[6], gc); gc = fmaf(h7, wb[7], gc);
        go = fmaf(h, wc[0], go); go = fmaf(h1, wc[1], go); go = fmaf(h2, wc[2], go); go = fmaf(h3, wc[3], go);
        go = fmaf(h4, wc[4], go); go = fmaf(h5, wc[5], go); go = fmaf(h6, wc[6], go); go = fmaf(h7, wc[7], go);
        float iv = fsig(gi);
        float cv = ftanh(gc);
        float ov = fsig(go);
        c = fmaf(fv, c, iv * cv);
        h = ov * ftanh(c);
        op[(size_t)t * 8] = h;
    }
}

extern "C" void kernel_launch(void* const* d_in, const int* in_sizes, int n_in,
                              void* d_out, int out_size, void* d_ws, size_t ws_size,
                              hipStream_t stream) {
    const float* x    = (const float*)d_in[0];  // (256,4096,3)
    const float* Wi   = (const float*)d_in[1];  // (3,24)
    const float* Wr   = (const float*)d_in[2];  // (8,24)
    const float* Wf   = (const float*)d_in[3];  // (21,8)
    const float* bias = (const float*)d_in[4];  // (32,)
    float* out = (float*)d_out;                 // (256,4096,8)

    const size_t need = (size_t)TT * BB * UU * 4 * sizeof(float);  // 128 MiB
    if (ws_size >= need) {
        sig_pre_kernel<<<dim3(BB), dim3(256), 0, stream>>>(x, Wi, Wf, bias, (float*)d_ws);
        lstm_scan_full<<<dim3(BB / 32), dim3(64), 0, stream>>>((const float*)d_ws, Wr, out);
    } else {
        lstm_scan_ultra<<<dim3(BB / 8), dim3(64), 0, stream>>>(x, Wi, Wr, Wf, bias, out);
    }
}

// Round 6
// 1048.557 us; speedup vs baseline: 1.8106x; 1.8106x over previous
//
#include <hip/hip_runtime.h>
#include <hip/hip_bf16.h>

#define TT 4096
#define BB 256
#define DD 3
#define UU 8

// ---------- fast activations ----------
#if defined(__has_builtin)
#if __has_builtin(__builtin_amdgcn_exp2f) && __has_builtin(__builtin_amdgcn_rcpf)
#define FAST_EXP2(x) __builtin_amdgcn_exp2f(x)
#define FAST_RCP(x)  __builtin_amdgcn_rcpf(x)
#endif
#endif
#ifndef FAST_EXP2
#define FAST_EXP2(x) exp2f(x)
#define FAST_RCP(x)  (1.0f / (x))
#endif

#define NLOG2E  (-1.4426950408889634f)
#define P2LOG2E ( 2.8853900817779268f)

__device__ __forceinline__ float fsig(float x) {
    float e = FAST_EXP2(NLOG2E * x);
    return FAST_RCP(1.0f + e);
}
__device__ __forceinline__ float ftanh(float x) {
    float e = FAST_EXP2(P2LOG2E * x);
    return 1.0f - 2.0f * FAST_RCP(1.0f + e);
}

// ---------- DPP helpers ----------
template <int CTRL>
__device__ __forceinline__ float dpp_f(float v) {
    int i = __builtin_bit_cast(int, v);
    i = __builtin_amdgcn_update_dpp(0, i, CTRL, 0xF, 0xF, true);
    return __builtin_bit_cast(float, i);
}

// ---------- block-wide exclusive scan over 256 threads (R1/R2 verbatim) ----------
__device__ __forceinline__ float block_excl_scan(float v, int tid, float* red) {
    float x = v;
    int lid = tid & 63;
    #pragma unroll
    for (int d = 1; d < 64; d <<= 1) {
        float y = __shfl_up(x, d, 64);
        if (lid >= d) x += y;
    }
    int wave = tid >> 6;
    __syncthreads();
    if (lid == 63) red[wave] = x;
    __syncthreads();
    float off = 0.0f;
    for (int w = 0; w < wave; ++w) off += red[w];
    return off + (x - v);
}

// ---------- Kernel A: R1-measured-best structure; store applies exp2 pre-scales ----------
// ws layout: [t][b][u] float4 = {-L*gi_pre, 2L*gc_pre, -L*go_pre, f_sigmoided}
__global__ __launch_bounds__(256) void sig_pre_kernel(
    const float* __restrict__ x,     // (B,T,3)
    const float* __restrict__ Wi,    // (3,24)
    const float* __restrict__ Wf,    // (21,8)
    const float* __restrict__ bias,  // (32)
    float* __restrict__ ws)
{
    __shared__ float sWf[21 * 8];
    __shared__ float sWi[3 * 24];
    __shared__ float sB[32];
    __shared__ float red[4];

    const int tid = threadIdx.x;
    const int b = blockIdx.x;
    if (tid < 168) sWf[tid] = Wf[tid];
    if (tid < 72)  sWi[tid] = Wi[tid];
    if (tid < 32)  sB[tid]  = bias[tid];
    __syncthreads();

    const float dtc = 1.0f / 4095.0f;
    const int t0 = tid * 16;
    const float* xb = x + (size_t)b * TT * DD;

    float l1[4] = {0.f, 0.f, 0.f, 0.f};
    float l2[16];
    #pragma unroll
    for (int i = 0; i < 16; ++i) l2[i] = 0.f;
    {
        int s = (tid == 0) ? 1 : t0;
        float xp0 = xb[(s - 1) * 3 + 0];
        float xp1 = xb[(s - 1) * 3 + 1];
        float xp2 = xb[(s - 1) * 3 + 2];
        for (; s < t0 + 16; ++s) {
            float c0 = xb[s * 3 + 0], c1 = xb[s * 3 + 1], c2 = xb[s * 3 + 2];
            float dxv[4] = {dtc, c0 - xp0, c1 - xp1, c2 - xp2};
            #pragma unroll
            for (int r = 0; r < 4; ++r) {
                float tr = l1[r] + 0.5f * dxv[r];
                #pragma unroll
                for (int cc = 0; cc < 4; ++cc)
                    l2[r * 4 + cc] = fmaf(tr, dxv[cc], l2[r * 4 + cc]);
            }
            #pragma unroll
            for (int r = 0; r < 4; ++r) l1[r] += dxv[r];
            xp0 = c0; xp1 = c1; xp2 = c2;
        }
    }

    float S1[4], O1[4];
    #pragma unroll
    for (int r = 0; r < 4; ++r) { S1[r] = l1[r]; }
    for (int r = 0; r < 4; ++r) O1[r] = block_excl_scan(S1[r], tid, red);
    float O2[16];
    for (int rc = 0; rc < 16; ++rc) {
        float c2v = l2[rc] + O1[rc >> 2] * S1[rc & 3];
        O2[rc] = block_excl_scan(c2v, tid, red);
    }

    #pragma unroll
    for (int r = 0; r < 4; ++r) l1[r] = O1[r];
    #pragma unroll
    for (int i = 0; i < 16; ++i) l2[i] = O2[i];

    float xp0, xp1, xp2;
    {
        int tp = (tid == 0) ? 0 : (t0 - 1);
        xp0 = xb[tp * 3 + 0]; xp1 = xb[tp * 3 + 1]; xp2 = xb[tp * 3 + 2];
    }
    for (int i2 = 0; i2 < 16; ++i2) {
        const int t = t0 + i2;
        float c0 = xb[t * 3 + 0], c1 = xb[t * 3 + 1], c2 = xb[t * 3 + 2];
        if (t > 0) {
            float dxv[4] = {dtc, c0 - xp0, c1 - xp1, c2 - xp2};
            #pragma unroll
            for (int r = 0; r < 4; ++r) {
                float tr = l1[r] + 0.5f * dxv[r];
                #pragma unroll
                for (int cc = 0; cc < 4; ++cc)
                    l2[r * 4 + cc] = fmaf(tr, dxv[cc], l2[r * 4 + cc]);
            }
            #pragma unroll
            for (int r = 0; r < 4; ++r) l1[r] += dxv[r];
        }
        xp0 = c0; xp1 = c1; xp2 = c2;
        const float scale = (t == 0) ? 1.0f : (4095.0f / (float)t);
        float sg[21];
        sg[0] = scale;
        #pragma unroll
        for (int r = 0; r < 4; ++r) sg[1 + r] = l1[r] * scale;
        #pragma unroll
        for (int rc = 0; rc < 16; ++rc) sg[5 + rc] = l2[rc] * scale;

        float fa[8];
        #pragma unroll
        for (int u = 0; u < 8; ++u) fa[u] = sB[8 + u];
        #pragma unroll
        for (int j = 0; j < 21; ++j) {
            float s = sg[j];
            #pragma unroll
            for (int u = 0; u < 8; ++u) fa[u] = fmaf(s, sWf[j * 8 + u], fa[u]);
        }
        float g[24];
        #pragma unroll
        for (int u = 0; u < 8; ++u) {
            g[u] = sB[u]; g[8 + u] = sB[16 + u]; g[16 + u] = sB[24 + u];
        }
        #pragma unroll
        for (int gg = 0; gg < 24; ++gg) {
            g[gg] = fmaf(c0, sWi[gg], g[gg]);
            g[gg] = fmaf(c1, sWi[24 + gg], g[gg]);
            g[gg] = fmaf(c2, sWi[48 + gg], g[gg]);
        }
        float4* wp = (float4*)ws + ((size_t)t * BB + b) * UU;
        #pragma unroll
        for (int u = 0; u < 8; ++u)
            wp[u] = make_float4(NLOG2E * g[u], P2LOG2E * g[8 + u],
                                NLOG2E * g[16 + u], fsig(fa[u]));
    }
}

// ---------- Kernel B: 2-way interleaved recurrences per lane ----------
// lane = q*8+u; batches b0 = blk*16+q and b0+8. Ring depth 4 per chain:
// outstanding vmem = 4 rounds x (2 loads + 2 stores) = 16 << vmcnt limit.
__global__ __launch_bounds__(64) void lstm_scan_full(
    const float* __restrict__ ws, const float* __restrict__ Wr,
    float* __restrict__ out)
{
    const int lane = threadIdx.x;
    const int u = lane & 7;
    const int q = lane >> 3;
    const int b0 = blockIdx.x * 16 + q;
    // scaled weights: wa,wc *= -log2e ; wb *= 2log2e (source unit j = u^m)
    float wa[8], wb[8], wc[8];
    #pragma unroll
    for (int m = 0; m < 8; ++m) {
        int j = u ^ m;
        wa[m] = NLOG2E  * Wr[j * 24 + u];
        wb[m] = P2LOG2E * Wr[j * 24 + 8 + u];
        wc[m] = NLOG2E  * Wr[j * 24 + 16 + u];
    }
    const float4* gp0 = (const float4*)ws + (size_t)b0 * 8 + u;  // + t*2048
    const float4* gp1 = gp0 + 64;                                // batch b0+8
    float* op0 = out + (size_t)b0 * TT * 8 + u;
    float* op1 = op0 + (size_t)8 * TT * 8;
    float4 bufA[4], bufB[4];
    #pragma unroll
    for (int p = 0; p < 4; ++p) {
        bufA[p] = gp0[(size_t)p * 2048];
        bufB[p] = gp1[(size_t)p * 2048];
    }
    float h0 = 0.f, c0 = 0.f, h1 = 0.f, c1 = 0.f;

    auto step2 = [&](int t, int j, bool pf) {
        float4 ga = bufA[j];
        float4 gb = bufB[j];
        if (pf) {
            bufA[j] = gp0[(size_t)(t + 4) * 2048];
            bufB[j] = gp1[(size_t)(t + 4) * 2048];
        }
        // stage 1: DPP butterflies, both chains
        float A0 = h0, A1 = dpp_f<0xB1>(h0), A2 = dpp_f<0x4E>(h0), A3 = dpp_f<0x1B>(h0);
        float A7 = dpp_f<0x141>(h0), A6 = dpp_f<0xB1>(A7), A5 = dpp_f<0x4E>(A7), A4 = dpp_f<0x1B>(A7);
        float B0 = h1, B1 = dpp_f<0xB1>(h1), B2 = dpp_f<0x4E>(h1), B3 = dpp_f<0x1B>(h1);
        float B7 = dpp_f<0x141>(h1), B6 = dpp_f<0xB1>(B7), B5 = dpp_f<0x4E>(B7), B4 = dpp_f<0x1B>(B7);
        // stage 2: gate dots, two 4-chains each, interleaved across chains
        float giA = fmaf(A0, wa[0], ga.x), giA2 = A4 * wa[4];
        float gcA = fmaf(A0, wb[0], ga.y), gcA2 = A4 * wb[4];
        float goA = fmaf(A0, wc[0], ga.z), goA2 = A4 * wc[4];
        float giB = fmaf(B0, wa[0], gb.x), giB2 = B4 * wa[4];
        float gcB = fmaf(B0, wb[0], gb.y), gcB2 = B4 * wb[4];
        float goB = fmaf(B0, wc[0], gb.z), goB2 = B4 * wc[4];
        giA = fmaf(A1, wa[1], giA); giA2 = fmaf(A5, wa[5], giA2);
        gcA = fmaf(A1, wb[1], gcA); gcA2 = fmaf(A5, wb[5], gcA2);
        goA = fmaf(A1, wc[1], goA); goA2 = fmaf(A5, wc[5], goA2);
        giB = fmaf(B1, wa[1], giB); giB2 = fmaf(B5, wa[5], giB2);
        gcB = fmaf(B1, wb[1], gcB); gcB2 = fmaf(B5, wb[5], gcB2);
        goB = fmaf(B1, wc[1], goB); goB2 = fmaf(B5, wc[5], goB2);
        giA = fmaf(A2, wa[2], giA); giA2 = fmaf(A6, wa[6], giA2);
        gcA = fmaf(A2, wb[2], gcA); gcA2 = fmaf(A6, wb[6], gcA2);
        goA = fmaf(A2, wc[2], goA); goA2 = fmaf(A6, wc[6], goA2);
        giB = fmaf(B2, wa[2], giB); giB2 = fmaf(B6, wa[6], giB2);
        gcB = fmaf(B2, wb[2], gcB); gcB2 = fmaf(B6, wb[6], gcB2);
        goB = fmaf(B2, wc[2], goB); goB2 = fmaf(B6, wc[6], goB2);
        giA = fmaf(A3, wa[3], giA); giA2 = fmaf(A7, wa[7], giA2);
        gcA = fmaf(A3, wb[3], gcA); gcA2 = fmaf(A7, wb[7], gcA2);
        goA = fmaf(A3, wc[3], goA); goA2 = fmaf(A7, wc[7], goA2);
        giB = fmaf(B3, wa[3], giB); giB2 = fmaf(B7, wa[7], giB2);
        gcB = fmaf(B3, wb[3], gcB); gcB2 = fmaf(B7, wb[7], gcB2);
        goB = fmaf(B3, wc[3], goB); goB2 = fmaf(B7, wc[7], goB2);
        giA += giA2; gcA += gcA2; goA += goA2;
        giB += giB2; gcB += gcB2; goB += goB2;
        // stage 3: exp2 (pre-scaled args), both chains
        float eiA = FAST_EXP2(giA), ecA = FAST_EXP2(gcA), eoA = FAST_EXP2(goA);
        float eiB = FAST_EXP2(giB), ecB = FAST_EXP2(gcB), eoB = FAST_EXP2(goB);
        // stage 4: independent rcp paths (R2 algebra)
        float ivA = FAST_RCP(1.0f + eiA);
        float cvA = fmaf(-2.0f, FAST_RCP(1.0f + ecA), 1.0f);
        float ovA = FAST_RCP(1.0f + eoA);
        float ivB = FAST_RCP(1.0f + eiB);
        float cvB = fmaf(-2.0f, FAST_RCP(1.0f + ecB), 1.0f);
        float ovB = FAST_RCP(1.0f + eoB);
        c0 = fmaf(ga.w, c0, ivA * cvA);
        c1 = fmaf(gb.w, c1, ivB * cvB);
        // stage 5: tanh(c) and h
        float e2A = FAST_EXP2(P2LOG2E * c0);
        float e2B = FAST_EXP2(P2LOG2E * c1);
        h0 = ovA * fmaf(-2.0f, FAST_RCP(1.0f + e2A), 1.0f);
        h1 = ovB * fmaf(-2.0f, FAST_RCP(1.0f + e2B), 1.0f);
        op0[(size_t)t * 8] = h0;
        op1[(size_t)t * 8] = h1;
    };

    for (int tb = 0; tb < TT - 4; tb += 4) {
        #pragma unroll
        for (int j = 0; j < 4; ++j) step2(tb + j, j, true);
    }
    #pragma unroll
    for (int j = 0; j < 4; ++j) step2(TT - 4 + j, j, false);
}

// ---------- Fallback: no-scratch single kernel (raw weights) ----------
__global__ __launch_bounds__(64) void lstm_scan_ultra(
    const float* __restrict__ x, const float* __restrict__ Wi,
    const float* __restrict__ Wr, const float* __restrict__ Wf,
    const float* __restrict__ bias, float* __restrict__ out)
{
    const int lane = threadIdx.x;
    const int u = lane & 7;
    const int q = lane >> 3;
    const int b = blockIdx.x * 8 + q;
    float wa[8], wb[8], wc[8];
    #pragma unroll
    for (int m = 0; m < 8; ++m) {
        int j = u ^ m;
        wa[m] = Wr[j * 24 + u];
        wb[m] = Wr[j * 24 + 8 + u];
        wc[m] = Wr[j * 24 + 16 + u];
    }
    float wia[3], wib[3], wic[3];
    #pragma unroll
    for (int k = 0; k < 3; ++k) {
        wia[k] = Wi[k * 24 + u];
        wib[k] = Wi[k * 24 + 8 + u];
        wic[k] = Wi[k * 24 + 16 + u];
    }
    float wf[21];
    #pragma unroll
    for (int j = 0; j < 21; ++j) wf[j] = Wf[j * 8 + u];
    const float bi = bias[u], bf = bias[8 + u], bc = bias[16 + u], bo = bias[24 + u];
    const float* xb = x + (size_t)b * TT * 3;
    float l1[4] = {0.f, 0.f, 0.f, 0.f};
    float l2[16];
    #pragma unroll
    for (int i = 0; i < 16; ++i) l2[i] = 0.f;
    float xp0 = xb[0], xp1 = xb[1], xp2 = xb[2];
    float h = 0.f, c = 0.f;
    float* op = out + (size_t)b * TT * 8 + u;
    const float dtc = 1.0f / 4095.0f;
    for (int t = 0; t < TT; ++t) {
        float c0 = xb[t * 3 + 0], c1 = xb[t * 3 + 1], c2 = xb[t * 3 + 2];
        if (t > 0) {
            float dxv[4] = {dtc, c0 - xp0, c1 - xp1, c2 - xp2};
            #pragma unroll
            for (int r = 0; r < 4; ++r) {
                float tr = l1[r] + 0.5f * dxv[r];
                #pragma unroll
                for (int cc = 0; cc < 4; ++cc)
                    l2[r * 4 + cc] = fmaf(tr, dxv[cc], l2[r * 4 + cc]);
            }
            #pragma unroll
            for (int r = 0; r < 4; ++r) l1[r] += dxv[r];
        }
        xp0 = c0; xp1 = c1; xp2 = c2;
        const float scale = (t == 0) ? 1.0f : (4095.0f / (float)t);
        float dot = wf[0];
        #pragma unroll
        for (int r = 0; r < 4; ++r) dot = fmaf(l1[r], wf[1 + r], dot);
        #pragma unroll
        for (int rc = 0; rc < 16; ++rc) dot = fmaf(l2[rc], wf[5 + rc], dot);
        float fv = fsig(fmaf(scale, dot, bf));
        float gi = bi, gc = bc, go = bo;
        gi = fmaf(c0, wia[0], gi); gi = fmaf(c1, wia[1], gi); gi = fmaf(c2, wia[2], gi);
        gc = fmaf(c0, wib[0], gc); gc = fmaf(c1, wib[1], gc); gc = fmaf(c2, wib[2], gc);
        go = fmaf(c0, wic[0], go); go = fmaf(c1, wic[1], go); go = fmaf(c2, wic[2], go);
        float h1 = dpp_f<0xB1>(h);
        float h2 = dpp_f<0x4E>(h);
        float h3 = dpp_f<0x1B>(h);
        float h7 = dpp_f<0x141>(h);
        float h6 = dpp_f<0xB1>(h7);
        float h5 = dpp_f<0x4E>(h7);
        float h4 = dpp_f<0x1B>(h7);
        gi = fmaf(h, wa[0], gi); gi = fmaf(h1, wa[1], gi); gi = fmaf(h2, wa[2], gi); gi = fmaf(h3, wa[3], gi);
        gi = fmaf(h4, wa[4], gi); gi = fmaf(h5, wa[5], gi); gi = fmaf(h6, wa[6], gi); gi = fmaf(h7, wa[7], gi);
        gc = fmaf(h, wb[0], gc); gc = fmaf(h1, wb[1], gc); gc = fmaf(h2, wb[2], gc); gc = fmaf(h3, wb[3], gc);
        gc = fmaf(h4, wb[4], gc); gc = fmaf(h5, wb[5], gc); gc = fmaf(h6, wb[6], gc); gc = fmaf(h7, wb[7], gc);
        go = fmaf(h, wc[0], go); go = fmaf(h1, wc[1], go); go = fmaf(h2, wc[2], go); go = fmaf(h3, wc[3], go);
        go = fmaf(h4, wc[4], go); go = fmaf(h5, wc[5], go); go = fmaf(h6, wc[6], go); go = fmaf(h7, wc[7], go);
        float iv = fsig(gi);
        float cv = ftanh(gc);
        float ov = fsig(go);
        c = fmaf(fv, c, iv * cv);
        h = ov * ftanh(c);
        op[(size_t)t * 8] = h;
    }
}

extern "C" void kernel_launch(void* const* d_in, const int* in_sizes, int n_in,
                              void* d_out, int out_size, void* d_ws, size_t ws_size,
                              hipStream_t stream) {
    const float* x    = (const float*)d_in[0];  // (256,4096,3)
    const float* Wi   = (const float*)d_in[1];  // (3,24)
    const float* Wr   = (const float*)d_in[2];  // (8,24)
    const float* Wf   = (const float*)d_in[3];  // (21,8)
    const float* bias = (const float*)d_in[4];  // (32,)
    float* out = (float*)d_out;                 // (256,4096,8)

    const size_t need = (size_t)TT * BB * UU * 4 * sizeof(float);  // 128 MiB
    if (ws_size >= need) {
        sig_pre_kernel<<<dim3(BB), dim3(256), 0, stream>>>(x, Wi, Wf, bias, (float*)d_ws);
        lstm_scan_full<<<dim3(BB / 16), dim3(64), 0, stream>>>((const float*)d_ws, Wr, out);
    } else {
        lstm_scan_ultra<<<dim3(BB / 8), dim3(64), 0, stream>>>(x, Wi, Wr, Wf, bias, out);
    }
}

// Round 7
// 1000.639 us; speedup vs baseline: 1.8973x; 1.0479x over previous
//
#include <hip/hip_runtime.h>
#include <hip/hip_bf16.h>

#define TT 4096
#define BB 256
#define DD 3
#define UU 8

// ---------- fast activations ----------
#if defined(__has_builtin)
#if __has_builtin(__builtin_amdgcn_exp2f) && __has_builtin(__builtin_amdgcn_rcpf)
#define FAST_EXP2(x) __builtin_amdgcn_exp2f(x)
#define FAST_RCP(x)  __builtin_amdgcn_rcpf(x)
#endif
#endif
#ifndef FAST_EXP2
#define FAST_EXP2(x) exp2f(x)
#define FAST_RCP(x)  (1.0f / (x))
#endif

#define NLOG2E  (-1.4426950408889634f)
#define P2LOG2E ( 2.8853900817779268f)

// scheduling fence: nothing moves across (forces static A/B interleave)
#define SB() __builtin_amdgcn_sched_barrier(0)

__device__ __forceinline__ float fsig(float x) {
    float e = FAST_EXP2(NLOG2E * x);
    return FAST_RCP(1.0f + e);
}
__device__ __forceinline__ float ftanh(float x) {
    float e = FAST_EXP2(P2LOG2E * x);
    return 1.0f - 2.0f * FAST_RCP(1.0f + e);
}

// ---------- DPP helpers ----------
template <int CTRL>
__device__ __forceinline__ float dpp_f(float v) {
    int i = __builtin_bit_cast(int, v);
    i = __builtin_amdgcn_update_dpp(0, i, CTRL, 0xF, 0xF, true);
    return __builtin_bit_cast(float, i);
}

// ---------- block-wide exclusive scan over 256 threads (R1/R2 verbatim) ----------
__device__ __forceinline__ float block_excl_scan(float v, int tid, float* red) {
    float x = v;
    int lid = tid & 63;
    #pragma unroll
    for (int d = 1; d < 64; d <<= 1) {
        float y = __shfl_up(x, d, 64);
        if (lid >= d) x += y;
    }
    int wave = tid >> 6;
    __syncthreads();
    if (lid == 63) red[wave] = x;
    __syncthreads();
    float off = 0.0f;
    for (int w = 0; w < wave; ++w) off += red[w];
    return off + (x - v);
}

// ---------- Kernel A: R1-measured-best structure; store applies exp2 pre-scales ----------
// ws layout: [t][b][u] float4 = {-L*gi_pre, 2L*gc_pre, -L*go_pre, f_sigmoided}
__global__ __launch_bounds__(256) void sig_pre_kernel(
    const float* __restrict__ x,     // (B,T,3)
    const float* __restrict__ Wi,    // (3,24)
    const float* __restrict__ Wf,    // (21,8)
    const float* __restrict__ bias,  // (32)
    float* __restrict__ ws)
{
    __shared__ float sWf[21 * 8];
    __shared__ float sWi[3 * 24];
    __shared__ float sB[32];
    __shared__ float red[4];

    const int tid = threadIdx.x;
    const int b = blockIdx.x;
    if (tid < 168) sWf[tid] = Wf[tid];
    if (tid < 72)  sWi[tid] = Wi[tid];
    if (tid < 32)  sB[tid]  = bias[tid];
    __syncthreads();

    const float dtc = 1.0f / 4095.0f;
    const int t0 = tid * 16;
    const float* xb = x + (size_t)b * TT * DD;

    float l1[4] = {0.f, 0.f, 0.f, 0.f};
    float l2[16];
    #pragma unroll
    for (int i = 0; i < 16; ++i) l2[i] = 0.f;
    {
        int s = (tid == 0) ? 1 : t0;
        float xp0 = xb[(s - 1) * 3 + 0];
        float xp1 = xb[(s - 1) * 3 + 1];
        float xp2 = xb[(s - 1) * 3 + 2];
        for (; s < t0 + 16; ++s) {
            float c0 = xb[s * 3 + 0], c1 = xb[s * 3 + 1], c2 = xb[s * 3 + 2];
            float dxv[4] = {dtc, c0 - xp0, c1 - xp1, c2 - xp2};
            #pragma unroll
            for (int r = 0; r < 4; ++r) {
                float tr = l1[r] + 0.5f * dxv[r];
                #pragma unroll
                for (int cc = 0; cc < 4; ++cc)
                    l2[r * 4 + cc] = fmaf(tr, dxv[cc], l2[r * 4 + cc]);
            }
            #pragma unroll
            for (int r = 0; r < 4; ++r) l1[r] += dxv[r];
            xp0 = c0; xp1 = c1; xp2 = c2;
        }
    }

    float S1[4], O1[4];
    #pragma unroll
    for (int r = 0; r < 4; ++r) { S1[r] = l1[r]; }
    for (int r = 0; r < 4; ++r) O1[r] = block_excl_scan(S1[r], tid, red);
    float O2[16];
    for (int rc = 0; rc < 16; ++rc) {
        float c2v = l2[rc] + O1[rc >> 2] * S1[rc & 3];
        O2[rc] = block_excl_scan(c2v, tid, red);
    }

    #pragma unroll
    for (int r = 0; r < 4; ++r) l1[r] = O1[r];
    #pragma unroll
    for (int i = 0; i < 16; ++i) l2[i] = O2[i];

    float xp0, xp1, xp2;
    {
        int tp = (tid == 0) ? 0 : (t0 - 1);
        xp0 = xb[tp * 3 + 0]; xp1 = xb[tp * 3 + 1]; xp2 = xb[tp * 3 + 2];
    }
    for (int i2 = 0; i2 < 16; ++i2) {
        const int t = t0 + i2;
        float c0 = xb[t * 3 + 0], c1 = xb[t * 3 + 1], c2 = xb[t * 3 + 2];
        if (t > 0) {
            float dxv[4] = {dtc, c0 - xp0, c1 - xp1, c2 - xp2};
            #pragma unroll
            for (int r = 0; r < 4; ++r) {
                float tr = l1[r] + 0.5f * dxv[r];
                #pragma unroll
                for (int cc = 0; cc < 4; ++cc)
                    l2[r * 4 + cc] = fmaf(tr, dxv[cc], l2[r * 4 + cc]);
            }
            #pragma unroll
            for (int r = 0; r < 4; ++r) l1[r] += dxv[r];
        }
        xp0 = c0; xp1 = c1; xp2 = c2;
        const float scale = (t == 0) ? 1.0f : (4095.0f / (float)t);
        float sg[21];
        sg[0] = scale;
        #pragma unroll
        for (int r = 0; r < 4; ++r) sg[1 + r] = l1[r] * scale;
        #pragma unroll
        for (int rc = 0; rc < 16; ++rc) sg[5 + rc] = l2[rc] * scale;

        float fa[8];
        #pragma unroll
        for (int u = 0; u < 8; ++u) fa[u] = sB[8 + u];
        #pragma unroll
        for (int j = 0; j < 21; ++j) {
            float s = sg[j];
            #pragma unroll
            for (int u = 0; u < 8; ++u) fa[u] = fmaf(s, sWf[j * 8 + u], fa[u]);
        }
        float g[24];
        #pragma unroll
        for (int u = 0; u < 8; ++u) {
            g[u] = sB[u]; g[8 + u] = sB[16 + u]; g[16 + u] = sB[24 + u];
        }
        #pragma unroll
        for (int gg = 0; gg < 24; ++gg) {
            g[gg] = fmaf(c0, sWi[gg], g[gg]);
            g[gg] = fmaf(c1, sWi[24 + gg], g[gg]);
            g[gg] = fmaf(c2, sWi[48 + gg], g[gg]);
        }
        float4* wp = (float4*)ws + ((size_t)t * BB + b) * UU;
        #pragma unroll
        for (int u = 0; u < 8; ++u)
            wp[u] = make_float4(NLOG2E * g[u], P2LOG2E * g[8 + u],
                                NLOG2E * g[16 + u], fsig(fa[u]));
    }
}

// ---------- Kernel B: 2-way interleave with COMPILER-PINNED stage schedule ----------
// lane = q*8+u; batches b0 = blk*16+q and b0+8. Ring depth 4 per chain.
// sched_barrier(0) between stages: each dependent pair is separated by the
// other chain's independent issue -> in-order wave never stalls long.
__global__ __launch_bounds__(64) void lstm_scan_full(
    const float* __restrict__ ws, const float* __restrict__ Wr,
    float* __restrict__ out)
{
    const int lane = threadIdx.x;
    const int u = lane & 7;
    const int q = lane >> 3;
    const int b0 = blockIdx.x * 16 + q;
    // scaled weights: wa,wc *= -log2e ; wb *= 2log2e (source unit j = u^m)
    float wa[8], wb[8], wc[8];
    #pragma unroll
    for (int m = 0; m < 8; ++m) {
        int j = u ^ m;
        wa[m] = NLOG2E  * Wr[j * 24 + u];
        wb[m] = P2LOG2E * Wr[j * 24 + 8 + u];
        wc[m] = NLOG2E  * Wr[j * 24 + 16 + u];
    }
    const float4* gp0 = (const float4*)ws + (size_t)b0 * 8 + u;  // + t*2048
    const float4* gp1 = gp0 + 64;                                // batch b0+8
    float* op0 = out + (size_t)b0 * TT * 8 + u;
    float* op1 = op0 + (size_t)8 * TT * 8;
    float4 bufA[4], bufB[4];
    #pragma unroll
    for (int p = 0; p < 4; ++p) {
        bufA[p] = gp0[(size_t)p * 2048];
        bufB[p] = gp1[(size_t)p * 2048];
    }
    float h0 = 0.f, c0 = 0.f, h1 = 0.f, c1 = 0.f;

    auto step2 = [&](int t, int j, bool pf) {
        float4 ga = bufA[j];
        float4 gb = bufB[j];
        SB();
        if (pf) {
            bufA[j] = gp0[(size_t)(t + 4) * 2048];
            bufB[j] = gp1[(size_t)(t + 4) * 2048];
        }
        SB();
        // ---- stage: all DPP butterflies (A and B, mutually independent) ----
        float A1 = dpp_f<0xB1>(h0), A2 = dpp_f<0x4E>(h0), A3 = dpp_f<0x1B>(h0), A7 = dpp_f<0x141>(h0);
        float B1 = dpp_f<0xB1>(h1), B2 = dpp_f<0x4E>(h1), B3 = dpp_f<0x1B>(h1), B7 = dpp_f<0x141>(h1);
        float A6 = dpp_f<0xB1>(A7), A5 = dpp_f<0x4E>(A7), A4 = dpp_f<0x1B>(A7);
        float B6 = dpp_f<0xB1>(B7), B5 = dpp_f<0x4E>(B7), B4 = dpp_f<0x1B>(B7);
        SB();
        // ---- dot level 0 ----
        float giA = fmaf(h0, wa[0], ga.x), giA2 = A4 * wa[4];
        float gcA = fmaf(h0, wb[0], ga.y), gcA2 = A4 * wb[4];
        float goA = fmaf(h0, wc[0], ga.z), goA2 = A4 * wc[4];
        float giB = fmaf(h1, wa[0], gb.x), giB2 = B4 * wa[4];
        float gcB = fmaf(h1, wb[0], gb.y), gcB2 = B4 * wb[4];
        float goB = fmaf(h1, wc[0], gb.z), goB2 = B4 * wc[4];
        SB();
        // ---- dot level 1 ----
        giA = fmaf(A1, wa[1], giA); giA2 = fmaf(A5, wa[5], giA2);
        gcA = fmaf(A1, wb[1], gcA); gcA2 = fmaf(A5, wb[5], gcA2);
        goA = fmaf(A1, wc[1], goA); goA2 = fmaf(A5, wc[5], goA2);
        giB = fmaf(B1, wa[1], giB); giB2 = fmaf(B5, wa[5], giB2);
        gcB = fmaf(B1, wb[1], gcB); gcB2 = fmaf(B5, wb[5], gcB2);
        goB = fmaf(B1, wc[1], goB); goB2 = fmaf(B5, wc[5], goB2);
        SB();
        // ---- dot level 2 ----
        giA = fmaf(A2, wa[2], giA); giA2 = fmaf(A6, wa[6], giA2);
        gcA = fmaf(A2, wb[2], gcA); gcA2 = fmaf(A6, wb[6], gcA2);
        goA = fmaf(A2, wc[2], goA); goA2 = fmaf(A6, wc[6], goA2);
        giB = fmaf(B2, wa[2], giB); giB2 = fmaf(B6, wa[6], giB2);
        gcB = fmaf(B2, wb[2], gcB); gcB2 = fmaf(B6, wb[6], gcB2);
        goB = fmaf(B2, wc[2], goB); goB2 = fmaf(B6, wc[6], goB2);
        SB();
        // ---- dot level 3 ----
        giA = fmaf(A3, wa[3], giA); giA2 = fmaf(A7, wa[7], giA2);
        gcA = fmaf(A3, wb[3], gcA); gcA2 = fmaf(A7, wb[7], gcA2);
        goA = fmaf(A3, wc[3], goA); goA2 = fmaf(A7, wc[7], goA2);
        giB = fmaf(B3, wa[3], giB); giB2 = fmaf(B7, wa[7], giB2);
        gcB = fmaf(B3, wb[3], gcB); gcB2 = fmaf(B7, wb[7], gcB2);
        goB = fmaf(B3, wc[3], goB); goB2 = fmaf(B7, wc[7], goB2);
        SB();
        // ---- combine halves ----
        giA += giA2; gcA += gcA2; goA += goA2;
        giB += giB2; gcB += gcB2; goB += goB2;
        SB();
        // ---- exp2 (args pre-scaled) ----
        float eiA = FAST_EXP2(giA), ecA = FAST_EXP2(gcA), eoA = FAST_EXP2(goA);
        float eiB = FAST_EXP2(giB), ecB = FAST_EXP2(gcB), eoB = FAST_EXP2(goB);
        SB();
        // ---- 1 + e ----
        float diA = 1.0f + eiA, dcA = 1.0f + ecA, doA = 1.0f + eoA;
        float diB = 1.0f + eiB, dcB = 1.0f + ecB, doB = 1.0f + eoB;
        SB();
        // ---- rcp ----
        float ivA = FAST_RCP(diA), rcA = FAST_RCP(dcA), ovA = FAST_RCP(doA);
        float ivB = FAST_RCP(diB), rcB = FAST_RCP(dcB), ovB = FAST_RCP(doB);
        SB();
        // ---- c update ----
        float cvA = fmaf(-2.0f, rcA, 1.0f);
        float cvB = fmaf(-2.0f, rcB, 1.0f);
        c0 = fmaf(ga.w, c0, ivA * cvA);
        c1 = fmaf(gb.w, c1, ivB * cvB);
        SB();
        // ---- tanh(c): exp stage ----
        float e2A = FAST_EXP2(P2LOG2E * c0);
        float e2B = FAST_EXP2(P2LOG2E * c1);
        SB();
        // ---- tanh(c): rcp stage ----
        float r2A = FAST_RCP(1.0f + e2A);
        float r2B = FAST_RCP(1.0f + e2B);
        SB();
        // ---- h ----
        h0 = ovA * fmaf(-2.0f, r2A, 1.0f);
        h1 = ovB * fmaf(-2.0f, r2B, 1.0f);
        SB();
        op0[(size_t)t * 8] = h0;
        op1[(size_t)t * 8] = h1;
    };

    for (int tb = 0; tb < TT - 4; tb += 4) {
        #pragma unroll
        for (int j = 0; j < 4; ++j) step2(tb + j, j, true);
    }
    #pragma unroll
    for (int j = 0; j < 4; ++j) step2(TT - 4 + j, j, false);
}

// ---------- Fallback: no-scratch single kernel (raw weights) ----------
__global__ __launch_bounds__(64) void lstm_scan_ultra(
    const float* __restrict__ x, const float* __restrict__ Wi,
    const float* __restrict__ Wr, const float* __restrict__ Wf,
    const float* __restrict__ bias, float* __restrict__ out)
{
    const int lane = threadIdx.x;
    const int u = lane & 7;
    const int q = lane >> 3;
    const int b = blockIdx.x * 8 + q;
    float wa[8], wb[8], wc[8];
    #pragma unroll
    for (int m = 0; m < 8; ++m) {
        int j = u ^ m;
        wa[m] = Wr[j * 24 + u];
        wb[m] = Wr[j * 24 + 8 + u];
        wc[m] = Wr[j * 24 + 16 + u];
    }
    float wia[3], wib[3], wic[3];
    #pragma unroll
    for (int k = 0; k < 3; ++k) {
        wia[k] = Wi[k * 24 + u];
        wib[k] = Wi[k * 24 + 8 + u];
        wic[k] = Wi[k * 24 + 16 + u];
    }
    float wf[21];
    #pragma unroll
    for (int j = 0; j < 21; ++j) wf[j] = Wf[j * 8 + u];
    const float bi = bias[u], bf = bias[8 + u], bc = bias[16 + u], bo = bias[24 + u];
    const float* xb = x + (size_t)b * TT * 3;
    float l1[4] = {0.f, 0.f, 0.f, 0.f};
    float l2[16];
    #pragma unroll
    for (int i = 0; i < 16; ++i) l2[i] = 0.f;
    float xp0 = xb[0], xp1 = xb[1], xp2 = xb[2];
    float h = 0.f, c = 0.f;
    float* op = out + (size_t)b * TT * 8 + u;
    const float dtc = 1.0f / 4095.0f;
    for (int t = 0; t < TT; ++t) {
        float c0 = xb[t * 3 + 0], c1 = xb[t * 3 + 1], c2 = xb[t * 3 + 2];
        if (t > 0) {
            float dxv[4] = {dtc, c0 - xp0, c1 - xp1, c2 - xp2};
            #pragma unroll
            for (int r = 0; r < 4; ++r) {
                float tr = l1[r] + 0.5f * dxv[r];
                #pragma unroll
                for (int cc = 0; cc < 4; ++cc)
                    l2[r * 4 + cc] = fmaf(tr, dxv[cc], l2[r * 4 + cc]);
            }
            #pragma unroll
            for (int r = 0; r < 4; ++r) l1[r] += dxv[r];
        }
        xp0 = c0; xp1 = c1; xp2 = c2;
        const float scale = (t == 0) ? 1.0f : (4095.0f / (float)t);
        float dot = wf[0];
        #pragma unroll
        for (int r = 0; r < 4; ++r) dot = fmaf(l1[r], wf[1 + r], dot);
        #pragma unroll
        for (int rc = 0; rc < 16; ++rc) dot = fmaf(l2[rc], wf[5 + rc], dot);
        float fv = fsig(fmaf(scale, dot, bf));
        float gi = bi, gc = bc, go = bo;
        gi = fmaf(c0, wia[0], gi); gi = fmaf(c1, wia[1], gi); gi = fmaf(c2, wia[2], gi);
        gc = fmaf(c0, wib[0], gc); gc = fmaf(c1, wib[1], gc); gc = fmaf(c2, wib[2], gc);
        go = fmaf(c0, wic[0], go); go = fmaf(c1, wic[1], go); go = fmaf(c2, wic[2], go);
        float h1 = dpp_f<0xB1>(h);
        float h2 = dpp_f<0x4E>(h);
        float h3 = dpp_f<0x1B>(h);
        float h7 = dpp_f<0x141>(h);
        float h6 = dpp_f<0xB1>(h7);
        float h5 = dpp_f<0x4E>(h7);
        float h4 = dpp_f<0x1B>(h7);
        gi = fmaf(h, wa[0], gi); gi = fmaf(h1, wa[1], gi); gi = fmaf(h2, wa[2], gi); gi = fmaf(h3, wa[3], gi);
        gi = fmaf(h4, wa[4], gi); gi = fmaf(h5, wa[5], gi); gi = fmaf(h6, wa[6], gi); gi = fmaf(h7, wa[7], gi);
        gc = fmaf(h, wb[0], gc); gc = fmaf(h1, wb[1], gc); gc = fmaf(h2, wb[2], gc); gc = fmaf(h3, wb[3], gc);
        gc = fmaf(h4, wb[4], gc); gc = fmaf(h5, wb[5], gc); gc = fmaf(h6, wb[6], gc); gc = fmaf(h7, wb[7], gc);
        go = fmaf(h, wc[0], go); go = fmaf(h1, wc[1], go); go = fmaf(h2, wc[2], go); go = fmaf(h3, wc[3], go);
        go = fmaf(h4, wc[4], go); go = fmaf(h5, wc[5], go); go = fmaf(h6, wc[6], go); go = fmaf(h7, wc[7], go);
        float iv = fsig(gi);
        float cv = ftanh(gc);
        float ov = fsig(go);
        c = fmaf(fv, c, iv * cv);
        h = ov * ftanh(c);
        op[(size_t)t * 8] = h;
    }
}

extern "C" void kernel_launch(void* const* d_in, const int* in_sizes, int n_in,
                              void* d_out, int out_size, void* d_ws, size_t ws_size,
                              hipStream_t stream) {
    const float* x    = (const float*)d_in[0];  // (256,4096,3)
    const float* Wi   = (const float*)d_in[1];  // (3,24)
    const float* Wr   = (const float*)d_in[2];  // (8,24)
    const float* Wf   = (const float*)d_in[3];  // (21,8)
    const float* bias = (const float*)d_in[4];  // (32,)
    float* out = (float*)d_out;                 // (256,4096,8)

    const size_t need = (size_t)TT * BB * UU * 4 * sizeof(float);  // 128 MiB
    if (ws_size >= need) {
        sig_pre_kernel<<<dim3(BB), dim3(256), 0, stream>>>(x, Wi, Wf, bias, (float*)d_ws);
        lstm_scan_full<<<dim3(BB / 16), dim3(64), 0, stream>>>((const float*)d_ws, Wr, out);
    } else {
        lstm_scan_ultra<<<dim3(BB / 8), dim3(64), 0, stream>>>(x, Wi, Wr, Wf, bias, out);
    }
}